// Round 2
// baseline (11441.589 us; speedup 1.0000x reference)
//
#include <hip/hip_runtime.h>

#define CH 128

typedef __attribute__((ext_vector_type(8))) short short8;
typedef __attribute__((ext_vector_type(4))) float floatx4;

__device__ __forceinline__ float bf2f(unsigned short u) {
    union { unsigned int i; float f; } v; v.i = ((unsigned int)u) << 16; return v.f;
}
__device__ __forceinline__ unsigned short f2bf(float f) {
    union { float f; unsigned int i; } v; v.f = f;
    unsigned int r = v.i + 0x7FFF + ((v.i >> 16) & 1);  // RNE
    return (unsigned short)(r >> 16);
}

// ---------------- utility kernels ----------------

__global__ __launch_bounds__(256) void k_zero_f4(float4* __restrict__ p, int n4) {
    int i = blockIdx.x * 256 + threadIdx.x;
    if (i < n4) p[i] = make_float4(0.f, 0.f, 0.f, 0.f);
}

__global__ __launch_bounds__(256) void k_copy16(const int4* __restrict__ s, int4* __restrict__ d, int n16) {
    int i = blockIdx.x * 256 + threadIdx.x;
    if (i < n16) d[i] = s[i];
}

__global__ __launch_bounds__(256) void k_f2bf(const float* __restrict__ in,
                                              unsigned short* __restrict__ out, int n) {
    int i = blockIdx.x * 256 + threadIdx.x;
    if (i < n) out[i] = f2bf(in[i]);
}

// W (nmat,128,128) f32 row-major (k,n) -> Wt (nmat,128,128) bf16 (n,k)
__global__ __launch_bounds__(256) void k_wt(const float* __restrict__ W,
                                            unsigned short* __restrict__ Wt, int nmat) {
    int i = blockIdx.x * 256 + threadIdx.x;
    if (i >= (nmat << 14)) return;
    int mat = i >> 14, rem = i & 16383;
    int k = rem >> 7, n = rem & 127;
    Wt[(mat << 14) + (n << 7) + k] = f2bf(W[i]);
}

// ---------------- GEMM: Y(MxC) = A(MxC) @ B(CxC), A bf16 row-major, Bt bf16 N-major ----------------
// 128x128 tile, 256 threads = 4 waves x 32 rows. K=128 fully staged.
// LDS: XOR-swizzled 16B chunks, zero padding, exactly 64 KiB total.

__device__ __forceinline__ int lds_idx(int r, int koff) {
    return (r << 7) + ((((koff >> 3) ^ (r & 15))) << 3);
}

__global__ __launch_bounds__(256) void k_gemm(const unsigned short* __restrict__ A,
                                              const unsigned short* __restrict__ Bt,
                                              unsigned short* __restrict__ Y, int M) {
    __shared__ __align__(16) unsigned short sA[128 * 128];
    __shared__ __align__(16) unsigned short sB[128 * 128];
    const int t = threadIdx.x;
    const int row0 = blockIdx.x * 128;

    for (int it = 0; it < 8; ++it) {
        int chunk = it * 256 + t;       // 2048 chunks of 8 elems (16B)
        int r = chunk >> 4;
        int coff = (chunk & 15) << 3;
        int sidx = (r << 7) + ((((chunk & 15) ^ (r & 15))) << 3);
        float4 bv = *(const float4*)(Bt + (r << 7) + coff);
        *(float4*)(&sB[sidx]) = bv;
        int gr = row0 + r;
        float4 av = make_float4(0.f, 0.f, 0.f, 0.f);
        if (gr < M) av = *(const float4*)(A + (size_t)gr * CH + coff);
        *(float4*)(&sA[sidx]) = av;
    }
    __syncthreads();

    const int wave = t >> 6;
    const int lane = t & 63;
    const int quad = lane >> 4;
    const int l16  = lane & 15;
    const int rbase = wave * 32;

    floatx4 acc[2][8];
    for (int i = 0; i < 2; ++i)
        for (int j = 0; j < 8; ++j) acc[i][j] = (floatx4){0.f, 0.f, 0.f, 0.f};

    for (int kk = 0; kk < 4; ++kk) {
        int ko = kk * 32 + quad * 8;
        short8 a0 = *(const short8*)(&sA[lds_idx(rbase + l16, ko)]);
        short8 a1 = *(const short8*)(&sA[lds_idx(rbase + 16 + l16, ko)]);
        for (int j = 0; j < 8; ++j) {
            short8 b = *(const short8*)(&sB[lds_idx(j * 16 + l16, ko)]);
            acc[0][j] = __builtin_amdgcn_mfma_f32_16x16x32_bf16(a0, b, acc[0][j], 0, 0, 0);
            acc[1][j] = __builtin_amdgcn_mfma_f32_16x16x32_bf16(a1, b, acc[1][j], 0, 0, 0);
        }
    }

    for (int i = 0; i < 2; ++i) {
        int rg0 = row0 + rbase + i * 16 + quad * 4;
        for (int reg = 0; reg < 4; ++reg) {
            int rg = rg0 + reg;
            if (rg >= M) continue;
            unsigned short* yr = Y + (size_t)rg * CH;
            for (int j = 0; j < 8; ++j)
                yr[j * 16 + l16] = f2bf(acc[i][j][reg]);
        }
    }
}

// ---------------- SpMM scatter: m[row[e]] += val[e] * Y[col[e]]  ----------------
// one thread per (edge, 4 channels)

__global__ __launch_bounds__(256) void k_scatter(const int* __restrict__ row,
                                                 const int* __restrict__ col,
                                                 const float* __restrict__ val,
                                                 const unsigned short* __restrict__ Y,
                                                 float* __restrict__ m, int nnz) {
    int tid = blockIdx.x * 256 + threadIdx.x;
    int e = tid >> 5;
    if (e >= nnz) return;
    int q = (tid & 31) << 2;
    int r = row[e];
    int c = col[e];
    float v = val[e];
    ushort4 y4 = *(const ushort4*)(Y + (size_t)c * CH + q);
    float* mp = m + (size_t)r * CH + q;
    unsafeAtomicAdd(mp + 0, v * bf2f(y4.x));
    unsafeAtomicAdd(mp + 1, v * bf2f(y4.y));
    unsafeAtomicAdd(mp + 2, v * bf2f(y4.z));
    unsafeAtomicAdd(mp + 3, v * bf2f(y4.w));
}

// ---------------- sigmoid + cast to bf16 (in-place overwrite of x) ----------------

__global__ __launch_bounds__(256) void k_sigmoid(const float* __restrict__ m,
                                                 unsigned short* __restrict__ x, int n) {
    int i = blockIdx.x * 256 + threadIdx.x;
    if (i < n) {
        float s = 1.0f / (1.0f + __expf(-m[i]));
        x[i] = f2bf(s);
    }
}

// ---------------- output head ----------------

__global__ __launch_bounds__(128) void k_out(const unsigned short* __restrict__ x0,
                                             const float* __restrict__ Wout,
                                             const float* __restrict__ bout,
                                             float* __restrict__ out, int M) {
    __shared__ float sl[8][16];
    int rlocal = threadIdx.x >> 4;
    int o = threadIdx.x & 15;
    int rowi = blockIdx.x * 8 + rlocal;
    float acc = 0.f;
    if (rowi < M && o < 10) {
        const unsigned short* xr = x0 + (size_t)rowi * CH;
        for (int k = 0; k < CH; ++k)
            acc += bf2f(xr[k]) * Wout[k * 10 + o];
        acc += bout[o];
    }
    sl[rlocal][o] = acc;
    __syncthreads();
    if (rowi < M && o < 10) {
        float mx = -1e30f;
        for (int j = 0; j < 10; ++j) mx = fmaxf(mx, sl[rlocal][j]);
        float s = 0.f;
        for (int j = 0; j < 10; ++j) s += __expf(sl[rlocal][j] - mx);
        out[rowi * 10 + o] = __expf(sl[rlocal][o] - mx) / s;
    }
}

// ---------------- launch ----------------

extern "C" void kernel_launch(void* const* d_in, const int* in_sizes, int n_in,
                              void* d_out, int out_size, void* d_ws, size_t ws_size,
                              hipStream_t stream) {
    const float* xin[4];
    for (int r = 0; r < 4; ++r) xin[r] = (const float*)d_in[r];
    const int* arow[4]; const int* acol[4]; const float* aval[4];
    for (int r = 0; r < 4; ++r) {
        arow[r] = (const int*)d_in[4 + 3 * r];
        acol[r] = (const int*)d_in[5 + 3 * r];
        aval[r] = (const float*)d_in[6 + 3 * r];
    }
    const int* irow[3]; const int* icol[3]; const float* ival[3];
    for (int r = 0; r < 3; ++r) {
        irow[r] = (const int*)d_in[16 + 3 * r];
        icol[r] = (const int*)d_in[17 + 3 * r];
        ival[r] = (const float*)d_in[18 + 3 * r];
    }
    const float* W_same = (const float*)d_in[25];
    const float* W_h2l  = (const float*)d_in[26];
    const float* W_l2h  = (const float*)d_in[27];
    const float* W_out  = (const float*)d_in[28];
    const float* b_out  = (const float*)d_in[29];

    int Nr[4], adjnnz[4], incnnz[3];
    for (int r = 0; r < 4; ++r) { Nr[r] = in_sizes[r] / CH; adjnnz[r] = in_sizes[4 + 3 * r]; }
    for (int r = 0; r < 3; ++r) incnnz[r] = in_sizes[16 + 3 * r];
    int Nmax = 0;
    for (int r = 0; r < 4; ++r) if (Nr[r] > Nmax) Nmax = Nr[r];
    size_t totalN = (size_t)Nr[0] + Nr[1] + Nr[2] + Nr[3];

    // ---- workspace layout (~190 MB) ----
    char* ws = (char*)d_ws;
    size_t off = 0;
    auto take = [&](size_t bytes) { char* p = ws + off; off += (bytes + 255) & ~(size_t)255; return p; };
    unsigned short* xbuf  = (unsigned short*)take(totalN * CH * 2);         // 66.6 MB
    unsigned short* xsave = (unsigned short*)take((size_t)Nmax * CH * 2);   // 30.7 MB
    float*          mbuf  = (float*)take((size_t)Nmax * CH * 4);            // 61.4 MB
    unsigned short* ybuf  = (unsigned short*)take((size_t)Nmax * CH * 2);   // 30.7 MB
    unsigned short* WsT   = (unsigned short*)take((size_t)8 * 16384 * 2);
    unsigned short* WhT   = (unsigned short*)take((size_t)6 * 16384 * 2);
    unsigned short* WlT   = (unsigned short*)take((size_t)6 * 16384 * 2);
    (void)ws_size;

    unsigned short* x[4];
    {
        size_t o = 0;
        for (int r = 0; r < 4; ++r) { x[r] = xbuf + o; o += (size_t)Nr[r] * CH; }
    }

    // input conversion + weight transpose/convert
    for (int r = 0; r < 4; ++r) {
        int n = Nr[r] * CH;
        k_f2bf<<<(n + 255) / 256, 256, 0, stream>>>(xin[r], x[r], n);
    }
    k_wt<<<(8 * 16384 + 255) / 256, 256, 0, stream>>>(W_same, WsT, 8);
    k_wt<<<(6 * 16384 + 255) / 256, 256, 0, stream>>>(W_h2l, WhT, 6);
    k_wt<<<(6 * 16384 + 255) / 256, 256, 0, stream>>>(W_l2h, WlT, 6);

    for (int l = 0; l < 2; ++l) {
        for (int r = 0; r < 4; ++r) {
            int M = Nr[r];
            // zero the accumulator
            k_zero_f4<<<(M * 32 + 255) / 256, 256, 0, stream>>>((float4*)mbuf, M * 32);

            // same-rank: adj_r @ (x_r W_same)
            k_gemm<<<(M + 127) / 128, 256, 0, stream>>>(x[r], WsT + (((size_t)(l * 4 + r)) << 14), ybuf, M);
            {
                long T = (long)adjnnz[r] * 32;
                k_scatter<<<(T + 255) / 256, 256, 0, stream>>>(arow[r], acol[r], aval[r], ybuf, mbuf, adjnnz[r]);
            }
            // high-to-low: inc_{r+1} @ (x_{r+1} W_h2l)   (x_{r+1} not yet overwritten)
            if (r < 3) {
                int Ms = Nr[r + 1];
                k_gemm<<<(Ms + 127) / 128, 256, 0, stream>>>(x[r + 1], WhT + (((size_t)(l * 3 + r)) << 14), ybuf, Ms);
                long T = (long)incnnz[r] * 32;
                k_scatter<<<(T + 255) / 256, 256, 0, stream>>>(irow[r], icol[r], ival[r], ybuf, mbuf, incnnz[r]);
            }
            // low-to-high: inc_r^T @ (old x_{r-1} W_l2h)  (old x_{r-1} preserved in xsave)
            if (r > 0) {
                int Ms = Nr[r - 1];
                k_gemm<<<(Ms + 127) / 128, 256, 0, stream>>>(xsave, WlT + (((size_t)(l * 3 + r - 1)) << 14), ybuf, Ms);
                long T = (long)incnnz[r - 1] * 32;
                k_scatter<<<(T + 255) / 256, 256, 0, stream>>>(icol[r - 1], irow[r - 1], ival[r - 1], ybuf, mbuf, incnnz[r - 1]);
            }
            // preserve old x_r for rank r+1's l2h, then overwrite x_r in place
            if (r < 3) {
                int n16 = M * 16;  // M*128 bf16 elems = M*16 int4
                k_copy16<<<(n16 + 255) / 256, 256, 0, stream>>>((const int4*)x[r], (int4*)xsave, n16);
            }
            int n = M * CH;
            k_sigmoid<<<(n + 255) / 256, 256, 0, stream>>>(mbuf, x[r], n);
        }
    }

    k_out<<<(Nr[0] + 7) / 8, 128, 0, stream>>>(x[0], W_out, b_out, (float*)d_out, Nr[0]);
}

// Round 3
// 2413.936 us; speedup vs baseline: 4.7398x; 4.7398x over previous
//
#include <hip/hip_runtime.h>

#define CH 128

typedef __attribute__((ext_vector_type(8))) short short8;
typedef __attribute__((ext_vector_type(4))) float floatx4;

__device__ __forceinline__ float bf2f(unsigned short u) {
    union { unsigned int i; float f; } v; v.i = ((unsigned int)u) << 16; return v.f;
}
__device__ __forceinline__ unsigned short f2bf(float f) {
    union { float f; unsigned int i; } v; v.f = f;
    unsigned int r = v.i + 0x7FFF + ((v.i >> 16) & 1);  // RNE
    return (unsigned short)(r >> 16);
}

// ---------------- utility kernels ----------------

__global__ __launch_bounds__(256) void k_zero_i(int* __restrict__ p, int n) {
    int i = blockIdx.x * 256 + threadIdx.x;
    if (i < n) p[i] = 0;
}

__global__ __launch_bounds__(256) void k_copy16(const int4* __restrict__ s, int4* __restrict__ d, int n16) {
    int i = blockIdx.x * 256 + threadIdx.x;
    if (i < n16) d[i] = s[i];
}

__global__ __launch_bounds__(256) void k_f2bf(const float* __restrict__ in,
                                              unsigned short* __restrict__ out, int n) {
    int i = blockIdx.x * 256 + threadIdx.x;
    if (i < n) out[i] = f2bf(in[i]);
}

// W (nmat,128,128) f32 row-major (k,n) -> Wt (nmat,128,128) bf16 (n,k)
__global__ __launch_bounds__(256) void k_wt(const float* __restrict__ W,
                                            unsigned short* __restrict__ Wt, int nmat) {
    int i = blockIdx.x * 256 + threadIdx.x;
    if (i >= (nmat << 14)) return;
    int mat = i >> 14, rem = i & 16383;
    int k = rem >> 7, n = rem & 127;
    Wt[(mat << 14) + (n << 7) + k] = f2bf(W[i]);
}

// ---------------- CSR build ----------------

__global__ __launch_bounds__(256) void k_hist(const int* __restrict__ row, int* __restrict__ cnt, int nnz) {
    int i = blockIdx.x * 256 + threadIdx.x;
    if (i < nnz) atomicAdd(&cnt[row[i]], 1);
}

// single-block exclusive scan; cnt is read AND rewritten with the exclusive
// prefix (it then serves as the fill cursor). rowptr[0..n] fully written.
__global__ __launch_bounds__(1024) void k_scan(int* __restrict__ cnt, int* __restrict__ rowptr, int n) {
    __shared__ int swt[16];
    __shared__ int scarry;
    int t = threadIdx.x, lane = t & 63, w = t >> 6;
    if (t == 0) scarry = 0;
    __syncthreads();
    for (int base = 0; base < n; base += 1024) {
        int i = base + t;
        int v = (i < n) ? cnt[i] : 0;
        int incl = v;
        for (int off = 1; off < 64; off <<= 1) {
            int u = __shfl_up(incl, off, 64);
            if (lane >= off) incl += u;
        }
        if (lane == 63) swt[w] = incl;
        __syncthreads();
        int waveoff = 0;
        for (int k = 0; k < w; ++k) waveoff += swt[k];
        int running = scarry;
        int excl = running + waveoff + incl - v;
        if (i < n) { rowptr[i] = excl; cnt[i] = excl; }
        __syncthreads();                       // everyone has read scarry
        if (t == 1023) scarry = running + waveoff + incl;
        __syncthreads();
    }
    if (t == 0) rowptr[n] = scarry;
}

__global__ __launch_bounds__(256) void k_fill(const int* __restrict__ row, const int* __restrict__ col,
                                              const float* __restrict__ val, int* __restrict__ cursor,
                                              int2* __restrict__ edg, int nnz) {
    int i = blockIdx.x * 256 + threadIdx.x;
    if (i >= nnz) return;
    int p = atomicAdd(&cursor[row[i]], 1);
    edg[p] = make_int2(col[i], __float_as_int(val[i]));
}

// ---------------- GEMM: Y(MxC) = A(MxC) @ B(CxC), A bf16 row-major, Bt bf16 N-major ----------------

__device__ __forceinline__ int lds_idx(int r, int koff) {
    return (r << 7) + ((((koff >> 3) ^ (r & 15))) << 3);
}

__global__ __launch_bounds__(256) void k_gemm(const unsigned short* __restrict__ A,
                                              const unsigned short* __restrict__ Bt,
                                              unsigned short* __restrict__ Y, int M) {
    __shared__ __align__(16) unsigned short sA[128 * 128];
    __shared__ __align__(16) unsigned short sB[128 * 128];
    const int t = threadIdx.x;
    const int row0 = blockIdx.x * 128;

    for (int it = 0; it < 8; ++it) {
        int chunk = it * 256 + t;
        int r = chunk >> 4;
        int coff = (chunk & 15) << 3;
        int sidx = (r << 7) + ((((chunk & 15) ^ (r & 15))) << 3);
        float4 bv = *(const float4*)(Bt + (r << 7) + coff);
        *(float4*)(&sB[sidx]) = bv;
        int gr = row0 + r;
        float4 av = make_float4(0.f, 0.f, 0.f, 0.f);
        if (gr < M) av = *(const float4*)(A + (size_t)gr * CH + coff);
        *(float4*)(&sA[sidx]) = av;
    }
    __syncthreads();

    const int wave = t >> 6;
    const int lane = t & 63;
    const int quad = lane >> 4;
    const int l16  = lane & 15;
    const int rbase = wave * 32;

    floatx4 acc[2][8];
    for (int i = 0; i < 2; ++i)
        for (int j = 0; j < 8; ++j) acc[i][j] = (floatx4){0.f, 0.f, 0.f, 0.f};

    for (int kk = 0; kk < 4; ++kk) {
        int ko = kk * 32 + quad * 8;
        short8 a0 = *(const short8*)(&sA[lds_idx(rbase + l16, ko)]);
        short8 a1 = *(const short8*)(&sA[lds_idx(rbase + 16 + l16, ko)]);
        for (int j = 0; j < 8; ++j) {
            short8 b = *(const short8*)(&sB[lds_idx(j * 16 + l16, ko)]);
            acc[0][j] = __builtin_amdgcn_mfma_f32_16x16x32_bf16(a0, b, acc[0][j], 0, 0, 0);
            acc[1][j] = __builtin_amdgcn_mfma_f32_16x16x32_bf16(a1, b, acc[1][j], 0, 0, 0);
        }
    }

    for (int i = 0; i < 2; ++i) {
        int rg0 = row0 + rbase + i * 16 + quad * 4;
        for (int reg = 0; reg < 4; ++reg) {
            int rg = rg0 + reg;
            if (rg >= M) continue;
            unsigned short* yr = Y + (size_t)rg * CH;
            for (int j = 0; j < 8; ++j)
                yr[j * 16 + l16] = f2bf(acc[i][j][reg]);
        }
    }
}

// ---------------- fused gather (adj + h2l + l2h) + sigmoid ----------------
// one wave per output row; lane handles channels {2*lane, 2*lane+1}

__global__ __launch_bounds__(256) void k_gather(
    const int* __restrict__ rpA, const int2* __restrict__ eA, const unsigned short* __restrict__ yS,
    const int* __restrict__ rpH, const int2* __restrict__ eH, const unsigned short* __restrict__ yH, int hasH,
    const int* __restrict__ rpL, const int2* __restrict__ eL, const unsigned short* __restrict__ yL, int hasL,
    unsigned short* __restrict__ xout, int M)
{
    int wrow = blockIdx.x * 4 + (threadIdx.x >> 6);
    if (wrow >= M) return;
    int lane = threadIdx.x & 63;
    int coff = lane * 2;
    float a0 = 0.f, a1 = 0.f;

    int jb = rpA[wrow], je = rpA[wrow + 1];
    for (int j = jb; j < je; ++j) {
        int2 e = eA[j];
        float v = __int_as_float(e.y);
        ushort2 y2 = *(const ushort2*)(yS + (size_t)e.x * CH + coff);
        a0 += v * bf2f(y2.x);
        a1 += v * bf2f(y2.y);
    }
    if (hasH) {
        jb = rpH[wrow]; je = rpH[wrow + 1];
        for (int j = jb; j < je; ++j) {
            int2 e = eH[j];
            float v = __int_as_float(e.y);
            ushort2 y2 = *(const ushort2*)(yH + (size_t)e.x * CH + coff);
            a0 += v * bf2f(y2.x);
            a1 += v * bf2f(y2.y);
        }
    }
    if (hasL) {
        jb = rpL[wrow]; je = rpL[wrow + 1];
        for (int j = jb; j < je; ++j) {
            int2 e = eL[j];
            float v = __int_as_float(e.y);
            ushort2 y2 = *(const ushort2*)(yL + (size_t)e.x * CH + coff);
            a0 += v * bf2f(y2.x);
            a1 += v * bf2f(y2.y);
        }
    }
    float s0 = 1.0f / (1.0f + __expf(-a0));
    float s1 = 1.0f / (1.0f + __expf(-a1));
    ushort2 o;
    o.x = f2bf(s0);
    o.y = f2bf(s1);
    *(ushort2*)(xout + (size_t)wrow * CH + coff) = o;
}

// ---------------- output head ----------------

__global__ __launch_bounds__(128) void k_out(const unsigned short* __restrict__ x0,
                                             const float* __restrict__ Wout,
                                             const float* __restrict__ bout,
                                             float* __restrict__ out, int M) {
    __shared__ float sl[8][16];
    int rlocal = threadIdx.x >> 4;
    int o = threadIdx.x & 15;
    int rowi = blockIdx.x * 8 + rlocal;
    float acc = 0.f;
    if (rowi < M && o < 10) {
        const unsigned short* xr = x0 + (size_t)rowi * CH;
        for (int k = 0; k < CH; ++k)
            acc += bf2f(xr[k]) * Wout[k * 10 + o];
        acc += bout[o];
    }
    sl[rlocal][o] = acc;
    __syncthreads();
    if (rowi < M && o < 10) {
        float mx = -1e30f;
        for (int j = 0; j < 10; ++j) mx = fmaxf(mx, sl[rlocal][j]);
        float s = 0.f;
        for (int j = 0; j < 10; ++j) s += __expf(sl[rlocal][j] - mx);
        out[rowi * 10 + o] = __expf(sl[rlocal][o] - mx) / s;
    }
}

// ---------------- launch ----------------

extern "C" void kernel_launch(void* const* d_in, const int* in_sizes, int n_in,
                              void* d_out, int out_size, void* d_ws, size_t ws_size,
                              hipStream_t stream) {
    const float* xin[4];
    for (int r = 0; r < 4; ++r) xin[r] = (const float*)d_in[r];
    const int* arow[4]; const int* acol[4]; const float* aval[4];
    for (int r = 0; r < 4; ++r) {
        arow[r] = (const int*)d_in[4 + 3 * r];
        acol[r] = (const int*)d_in[5 + 3 * r];
        aval[r] = (const float*)d_in[6 + 3 * r];
    }
    const int* irow[3]; const int* icol[3]; const float* ival[3];
    for (int r = 0; r < 3; ++r) {
        irow[r] = (const int*)d_in[16 + 3 * r];
        icol[r] = (const int*)d_in[17 + 3 * r];
        ival[r] = (const float*)d_in[18 + 3 * r];
    }
    const float* W_same = (const float*)d_in[25];
    const float* W_h2l  = (const float*)d_in[26];
    const float* W_l2h  = (const float*)d_in[27];
    const float* W_out  = (const float*)d_in[28];
    const float* b_out  = (const float*)d_in[29];

    int Nr[4], adjnnz[4], incnnz[3];
    for (int r = 0; r < 4; ++r) { Nr[r] = in_sizes[r] / CH; adjnnz[r] = in_sizes[4 + 3 * r]; }
    for (int r = 0; r < 3; ++r) incnnz[r] = in_sizes[16 + 3 * r];
    int Nmax = 0;
    for (int r = 0; r < 4; ++r) if (Nr[r] > Nmax) Nmax = Nr[r];
    size_t totalN = (size_t)Nr[0] + Nr[1] + Nr[2] + Nr[3];
    size_t totAdj = 0; for (int r = 0; r < 4; ++r) totAdj += adjnnz[r];
    size_t totInc = 0; for (int r = 0; r < 3; ++r) totInc += incnnz[r];

    // ---- workspace layout (~219 MB) ----
    char* ws = (char*)d_ws;
    size_t off = 0;
    auto take = [&](size_t bytes) { char* p = ws + off; off += (bytes + 255) & ~(size_t)255; return p; };
    unsigned short* xbuf  = (unsigned short*)take(totalN * CH * 2);         // 66.6 MB
    unsigned short* xsave = (unsigned short*)take((size_t)Nmax * CH * 2);   // 30.7 MB
    unsigned short* yS    = (unsigned short*)take((size_t)Nmax * CH * 2);   // 30.7 MB
    unsigned short* yH    = (unsigned short*)take((size_t)Nmax * CH * 2);   // 30.7 MB
    unsigned short* yL    = (unsigned short*)take((size_t)Nmax * CH * 2);   // 30.7 MB
    unsigned short* WsT   = (unsigned short*)take((size_t)8 * 16384 * 2);
    unsigned short* WhT   = (unsigned short*)take((size_t)6 * 16384 * 2);
    unsigned short* WlT   = (unsigned short*)take((size_t)6 * 16384 * 2);
    int* cntbuf = (int*)take((size_t)Nmax * 4);                             // scratch cnt/cursor
    // rowptr arena
    int* rpAdj[4]; int* rpIncR[3]; int* rpIncC[3];
    for (int r = 0; r < 4; ++r) rpAdj[r]  = (int*)take(((size_t)Nr[r] + 1) * 4);
    for (int s = 0; s < 3; ++s) rpIncR[s] = (int*)take(((size_t)Nr[s] + 1) * 4);     // rows of inc{s+1} in rank s
    for (int s = 0; s < 3; ++s) rpIncC[s] = (int*)take(((size_t)Nr[s + 1] + 1) * 4); // cols of inc{s+1} in rank s+1
    // edge arenas (int2 = col, val)
    int2* eAdj[4]; int2* eIncR[3]; int2* eIncC[3];
    for (int r = 0; r < 4; ++r) eAdj[r]  = (int2*)take((size_t)adjnnz[r] * 8);
    for (int s = 0; s < 3; ++s) eIncR[s] = (int2*)take((size_t)incnnz[s] * 8);
    for (int s = 0; s < 3; ++s) eIncC[s] = (int2*)take((size_t)incnnz[s] * 8);
    (void)ws_size;

    unsigned short* x[4];
    {
        size_t o = 0;
        for (int r = 0; r < 4; ++r) { x[r] = xbuf + o; o += (size_t)Nr[r] * CH; }
    }

    // ---- CSR builds (sequential; cntbuf reused as count+cursor) ----
    auto build = [&](const int* rsrc, const int* csrc, const float* vsrc, int nnz, int nrows,
                     int* rowptr, int2* edg) {
        k_zero_i<<<(nrows + 255) / 256, 256, 0, stream>>>(cntbuf, nrows);
        k_hist<<<(nnz + 255) / 256, 256, 0, stream>>>(rsrc, cntbuf, nnz);
        k_scan<<<1, 1024, 0, stream>>>(cntbuf, rowptr, nrows);
        k_fill<<<(nnz + 255) / 256, 256, 0, stream>>>(rsrc, csrc, vsrc, cntbuf, edg, nnz);
    };
    for (int r = 0; r < 4; ++r) build(arow[r], acol[r], aval[r], adjnnz[r], Nr[r], rpAdj[r], eAdj[r]);
    for (int s = 0; s < 3; ++s) build(irow[s], icol[s], ival[s], incnnz[s], Nr[s], rpIncR[s], eIncR[s]);
    for (int s = 0; s < 3; ++s) build(icol[s], irow[s], ival[s], incnnz[s], Nr[s + 1], rpIncC[s], eIncC[s]);

    // ---- input conversion + weight transpose/convert ----
    for (int r = 0; r < 4; ++r) {
        int n = Nr[r] * CH;
        k_f2bf<<<(n + 255) / 256, 256, 0, stream>>>(xin[r], x[r], n);
    }
    k_wt<<<(8 * 16384 + 255) / 256, 256, 0, stream>>>(W_same, WsT, 8);
    k_wt<<<(6 * 16384 + 255) / 256, 256, 0, stream>>>(W_h2l, WhT, 6);
    k_wt<<<(6 * 16384 + 255) / 256, 256, 0, stream>>>(W_l2h, WlT, 6);

    // ---- layers ----
    for (int l = 0; l < 2; ++l) {
        for (int r = 0; r < 4; ++r) {
            int M = Nr[r];
            // GEMMs (snapshots into yS / yH / yL)
            k_gemm<<<(M + 127) / 128, 256, 0, stream>>>(x[r], WsT + (((size_t)(l * 4 + r)) << 14), yS, M);
            if (r < 3) {
                int Ms = Nr[r + 1];
                k_gemm<<<(Ms + 127) / 128, 256, 0, stream>>>(x[r + 1], WhT + (((size_t)(l * 3 + r)) << 14), yH, Ms);
            }
            if (r > 0) {
                int Ms = Nr[r - 1];
                k_gemm<<<(Ms + 127) / 128, 256, 0, stream>>>(xsave, WlT + (((size_t)(l * 3 + r - 1)) << 14), yL, Ms);
            }
            // preserve old x_r for rank r+1's l2h BEFORE overwriting
            if (r < 3) {
                int n16 = M * 16;
                k_copy16<<<(n16 + 255) / 256, 256, 0, stream>>>((const int4*)x[r], (int4*)xsave, n16);
            }
            // fused gather + sigmoid, writes x[r]
            int hasH = (r < 3) ? 1 : 0;
            int hasL = (r > 0) ? 1 : 0;
            const int*  rpH = hasH ? rpIncR[r]     : rpAdj[r];
            const int2* eH  = hasH ? eIncR[r]      : eAdj[r];
            const int*  rpL = hasL ? rpIncC[r - 1] : rpAdj[r];
            const int2* eL  = hasL ? eIncC[r - 1]  : eAdj[r];
            k_gather<<<(M + 3) / 4, 256, 0, stream>>>(
                rpAdj[r], eAdj[r], yS,
                rpH, eH, yH, hasH,
                rpL, eL, yL, hasL,
                x[r], M);
        }
    }

    k_out<<<(Nr[0] + 7) / 8, 128, 0, stream>>>(x[0], W_out, b_out, (float*)d_out, Nr[0]);
}

// Round 4
// 1320.644 us; speedup vs baseline: 8.6636x; 1.8278x over previous
//
#include <hip/hip_runtime.h>

#define CH 128

typedef __attribute__((ext_vector_type(8))) short short8;
typedef __attribute__((ext_vector_type(4))) float floatx4;

__device__ __forceinline__ float bf2f(unsigned short u) {
    union { unsigned int i; float f; } v; v.i = ((unsigned int)u) << 16; return v.f;
}
__device__ __forceinline__ unsigned short f2bf(float f) {
    union { float f; unsigned int i; } v; v.f = f;
    unsigned int r = v.i + 0x7FFF + ((v.i >> 16) & 1);  // RNE
    return (unsigned short)(r >> 16);
}

// ---------------- utility kernels ----------------

__global__ __launch_bounds__(256) void k_zero_i(int* __restrict__ p, int n) {
    int i = blockIdx.x * 256 + threadIdx.x;
    if (i < n) p[i] = 0;
}

__global__ __launch_bounds__(256) void k_copy16(const int4* __restrict__ s, int4* __restrict__ d, int n16) {
    int i = blockIdx.x * 256 + threadIdx.x;
    if (i < n16) d[i] = s[i];
}

__global__ __launch_bounds__(256) void k_f2bf(const float* __restrict__ in,
                                              unsigned short* __restrict__ out, int n) {
    int i = blockIdx.x * 256 + threadIdx.x;
    if (i < n) out[i] = f2bf(in[i]);
}

// W (nmat,128,128) f32 row-major (k,n) -> Wt (nmat,128,128) bf16 (n,k)
__global__ __launch_bounds__(256) void k_wt(const float* __restrict__ W,
                                            unsigned short* __restrict__ Wt, int nmat) {
    int i = blockIdx.x * 256 + threadIdx.x;
    if (i >= (nmat << 14)) return;
    int mat = i >> 14, rem = i & 16383;
    int k = rem >> 7, n = rem & 127;
    Wt[(mat << 14) + (n << 7) + k] = f2bf(W[i]);
}

// ---------------- CSR build (concatenated, hierarchical scan) ----------------

__global__ __launch_bounds__(256) void k_hist(const int* __restrict__ row, int* __restrict__ cnt, int nnz) {
    int i = blockIdx.x * 256 + threadIdx.x;
    if (i < nnz) atomicAdd(&cnt[row[i]], 1);
}

// block b sums cnt[b*4096 .. b*4096+4095] -> part[b]
__global__ __launch_bounds__(256) void k_scan_partial(const int* __restrict__ cnt, int* __restrict__ part, int n) {
    __shared__ int swt[4];
    int t = threadIdx.x, lane = t & 63, w = t >> 6;
    int base = blockIdx.x * 4096 + t * 16;
    int s = 0;
#pragma unroll
    for (int k = 0; k < 16; ++k) {
        int i = base + k;
        if (i < n) s += cnt[i];
    }
    for (int off = 1; off < 64; off <<= 1) s += __shfl_xor(s, off, 64);
    if (lane == 0) swt[w] = s;
    __syncthreads();
    if (t == 0) part[blockIdx.x] = swt[0] + swt[1] + swt[2] + swt[3];
}

// single block: exclusive scan of part[0..nb) in place; *totalOut = total
__global__ __launch_bounds__(256) void k_scan_part(int* __restrict__ part, int nb, int* __restrict__ totalOut) {
    __shared__ int swt[4];
    __shared__ int scarry;
    int t = threadIdx.x, lane = t & 63, w = t >> 6;
    if (t == 0) scarry = 0;
    __syncthreads();
    for (int base = 0; base < nb; base += 256) {
        int i = base + t;
        int v = (i < nb) ? part[i] : 0;
        int incl = v;
        for (int off = 1; off < 64; off <<= 1) {
            int u = __shfl_up(incl, off, 64);
            if (lane >= off) incl += u;
        }
        if (lane == 63) swt[w] = incl;
        __syncthreads();
        int waveoff = 0;
        for (int k = 0; k < w; ++k) waveoff += swt[k];
        int running = scarry;
        if (i < nb) part[i] = running + waveoff + incl - v;
        __syncthreads();
        if (t == 255) scarry = running + waveoff + incl;
        __syncthreads();
    }
    if (t == 0) *totalOut = scarry;
}

// block b: exclusive rescan of its 4096-chunk + part[b]; writes rowptr and cursor
__global__ __launch_bounds__(256) void k_scan_final(const int* __restrict__ cnt, const int* __restrict__ part,
                                                    int* __restrict__ rowptr, int* __restrict__ cursor, int n) {
    __shared__ int swt[4];
    int t = threadIdx.x, lane = t & 63, w = t >> 6;
    int base = blockIdx.x * 4096 + t * 16;
    int v[16];
    int s = 0;
#pragma unroll
    for (int k = 0; k < 16; ++k) {
        int i = base + k;
        v[k] = (i < n) ? cnt[i] : 0;
        s += v[k];
    }
    int incl = s;
    for (int off = 1; off < 64; off <<= 1) {
        int u = __shfl_up(incl, off, 64);
        if (lane >= off) incl += u;
    }
    if (lane == 63) swt[w] = incl;
    __syncthreads();
    int waveoff = 0;
    for (int k = 0; k < w; ++k) waveoff += swt[k];
    int run = part[blockIdx.x] + waveoff + incl - s;
#pragma unroll
    for (int k = 0; k < 16; ++k) {
        int i = base + k;
        if (i < n) { rowptr[i] = run; cursor[i] = run; }
        run += v[k];
    }
}

__global__ __launch_bounds__(256) void k_fill(const int* __restrict__ row, const int* __restrict__ col,
                                              const float* __restrict__ val, int* __restrict__ cursor,
                                              int2* __restrict__ edg, int nnz) {
    int i = blockIdx.x * 256 + threadIdx.x;
    if (i >= nnz) return;
    int p = atomicAdd(&cursor[row[i]], 1);
    edg[p] = make_int2(col[i], __float_as_int(val[i]));
}

// ---------------- GEMM: Y(MxC) = A(MxC) @ B(CxC) ----------------

__device__ __forceinline__ int lds_idx(int r, int koff) {
    return (r << 7) + ((((koff >> 3) ^ (r & 15))) << 3);
}

__global__ __launch_bounds__(256) void k_gemm(const unsigned short* __restrict__ A,
                                              const unsigned short* __restrict__ Bt,
                                              unsigned short* __restrict__ Y, int M) {
    __shared__ __align__(16) unsigned short sA[128 * 128];
    __shared__ __align__(16) unsigned short sB[128 * 128];
    const int t = threadIdx.x;
    const int row0 = blockIdx.x * 128;

    for (int it = 0; it < 8; ++it) {
        int chunk = it * 256 + t;
        int r = chunk >> 4;
        int coff = (chunk & 15) << 3;
        int sidx = (r << 7) + ((((chunk & 15) ^ (r & 15))) << 3);
        float4 bv = *(const float4*)(Bt + (r << 7) + coff);
        *(float4*)(&sB[sidx]) = bv;
        int gr = row0 + r;
        float4 av = make_float4(0.f, 0.f, 0.f, 0.f);
        if (gr < M) av = *(const float4*)(A + (size_t)gr * CH + coff);
        *(float4*)(&sA[sidx]) = av;
    }
    __syncthreads();

    const int wave = t >> 6;
    const int lane = t & 63;
    const int quad = lane >> 4;
    const int l16  = lane & 15;
    const int rbase = wave * 32;

    floatx4 acc[2][8];
    for (int i = 0; i < 2; ++i)
        for (int j = 0; j < 8; ++j) acc[i][j] = (floatx4){0.f, 0.f, 0.f, 0.f};

    for (int kk = 0; kk < 4; ++kk) {
        int ko = kk * 32 + quad * 8;
        short8 a0 = *(const short8*)(&sA[lds_idx(rbase + l16, ko)]);
        short8 a1 = *(const short8*)(&sA[lds_idx(rbase + 16 + l16, ko)]);
        for (int j = 0; j < 8; ++j) {
            short8 b = *(const short8*)(&sB[lds_idx(j * 16 + l16, ko)]);
            acc[0][j] = __builtin_amdgcn_mfma_f32_16x16x32_bf16(a0, b, acc[0][j], 0, 0, 0);
            acc[1][j] = __builtin_amdgcn_mfma_f32_16x16x32_bf16(a1, b, acc[1][j], 0, 0, 0);
        }
    }

    for (int i = 0; i < 2; ++i) {
        int rg0 = row0 + rbase + i * 16 + quad * 4;
        for (int reg = 0; reg < 4; ++reg) {
            int rg = rg0 + reg;
            if (rg >= M) continue;
            unsigned short* yr = Y + (size_t)rg * CH;
            for (int j = 0; j < 8; ++j)
                yr[j * 16 + l16] = f2bf(acc[i][j][reg]);
        }
    }
}

// ---------------- fused gather (adj + h2l + l2h) + sigmoid ----------------
// one wave per row; lane handles channels {2*lane, 2*lane+1}.
// edges prefetched cooperatively (one coalesced load per 64 edges), broadcast
// via shfl; 4-wide unroll keeps 4 y-row gathers in flight.

__device__ __forceinline__ void gseg(const int* __restrict__ rp, const int2* __restrict__ eg,
                                     const unsigned short* __restrict__ y,
                                     int wrow, int lane, int coff, float& a0, float& a1) {
    int jb = rp[wrow], je = rp[wrow + 1];
    for (int base = jb; base < je; base += 64) {
        int n = je - base;
        if (n > 64) n = 64;
        int2 myE = make_int2(0, 0);
        if (lane < n) myE = eg[base + lane];
        int j = 0;
        for (; j + 4 <= n; j += 4) {
            int c0 = __shfl(myE.x, j);
            int c1 = __shfl(myE.x, j + 1);
            int c2 = __shfl(myE.x, j + 2);
            int c3 = __shfl(myE.x, j + 3);
            float v0 = __int_as_float(__shfl(myE.y, j));
            float v1 = __int_as_float(__shfl(myE.y, j + 1));
            float v2 = __int_as_float(__shfl(myE.y, j + 2));
            float v3 = __int_as_float(__shfl(myE.y, j + 3));
            ushort2 y0 = *(const ushort2*)(y + (((size_t)c0) << 7) + coff);
            ushort2 y1 = *(const ushort2*)(y + (((size_t)c1) << 7) + coff);
            ushort2 y2 = *(const ushort2*)(y + (((size_t)c2) << 7) + coff);
            ushort2 y3 = *(const ushort2*)(y + (((size_t)c3) << 7) + coff);
            a0 += v0 * bf2f(y0.x); a1 += v0 * bf2f(y0.y);
            a0 += v1 * bf2f(y1.x); a1 += v1 * bf2f(y1.y);
            a0 += v2 * bf2f(y2.x); a1 += v2 * bf2f(y2.y);
            a0 += v3 * bf2f(y3.x); a1 += v3 * bf2f(y3.y);
        }
        for (; j < n; ++j) {
            int c = __shfl(myE.x, j);
            float v = __int_as_float(__shfl(myE.y, j));
            ushort2 yy = *(const ushort2*)(y + (((size_t)c) << 7) + coff);
            a0 += v * bf2f(yy.x); a1 += v * bf2f(yy.y);
        }
    }
}

__global__ __launch_bounds__(256) void k_gather(
    const int* __restrict__ rpA, const unsigned short* __restrict__ yS,
    const int* __restrict__ rpH, const unsigned short* __restrict__ yH, int hasH,
    const int* __restrict__ rpL, const unsigned short* __restrict__ yL, int hasL,
    const int2* __restrict__ eArena,
    unsigned short* __restrict__ xout, int M)
{
    int wrow = blockIdx.x * 4 + (threadIdx.x >> 6);
    if (wrow >= M) return;
    int lane = threadIdx.x & 63;
    int coff = lane * 2;
    float a0 = 0.f, a1 = 0.f;

    gseg(rpA, eArena, yS, wrow, lane, coff, a0, a1);
    if (hasH) gseg(rpH, eArena, yH, wrow, lane, coff, a0, a1);
    if (hasL) gseg(rpL, eArena, yL, wrow, lane, coff, a0, a1);

    float s0 = 1.0f / (1.0f + __expf(-a0));
    float s1 = 1.0f / (1.0f + __expf(-a1));
    ushort2 o;
    o.x = f2bf(s0);
    o.y = f2bf(s1);
    *(ushort2*)(xout + (size_t)wrow * CH + coff) = o;
}

// ---------------- output head ----------------

__global__ __launch_bounds__(128) void k_out(const unsigned short* __restrict__ x0,
                                             const float* __restrict__ Wout,
                                             const float* __restrict__ bout,
                                             float* __restrict__ out, int M) {
    __shared__ float sl[8][16];
    int rlocal = threadIdx.x >> 4;
    int o = threadIdx.x & 15;
    int rowi = blockIdx.x * 8 + rlocal;
    float acc = 0.f;
    if (rowi < M && o < 10) {
        const unsigned short* xr = x0 + (size_t)rowi * CH;
        for (int k = 0; k < CH; ++k)
            acc += bf2f(xr[k]) * Wout[k * 10 + o];
        acc += bout[o];
    }
    sl[rlocal][o] = acc;
    __syncthreads();
    if (rowi < M && o < 10) {
        float mx = -1e30f;
        for (int j = 0; j < 10; ++j) mx = fmaxf(mx, sl[rlocal][j]);
        float s = 0.f;
        for (int j = 0; j < 10; ++j) s += __expf(sl[rlocal][j] - mx);
        out[rowi * 10 + o] = __expf(sl[rlocal][o] - mx) / s;
    }
}

// ---------------- launch ----------------

extern "C" void kernel_launch(void* const* d_in, const int* in_sizes, int n_in,
                              void* d_out, int out_size, void* d_ws, size_t ws_size,
                              hipStream_t stream) {
    const float* xin[4];
    for (int r = 0; r < 4; ++r) xin[r] = (const float*)d_in[r];
    const int* arow[4]; const int* acol[4]; const float* aval[4];
    for (int r = 0; r < 4; ++r) {
        arow[r] = (const int*)d_in[4 + 3 * r];
        acol[r] = (const int*)d_in[5 + 3 * r];
        aval[r] = (const float*)d_in[6 + 3 * r];
    }
    const int* irow[3]; const int* icol[3]; const float* ival[3];
    for (int r = 0; r < 3; ++r) {
        irow[r] = (const int*)d_in[16 + 3 * r];
        icol[r] = (const int*)d_in[17 + 3 * r];
        ival[r] = (const float*)d_in[18 + 3 * r];
    }
    const float* W_same = (const float*)d_in[25];
    const float* W_h2l  = (const float*)d_in[26];
    const float* W_l2h  = (const float*)d_in[27];
    const float* W_out  = (const float*)d_in[28];
    const float* b_out  = (const float*)d_in[29];

    int Nr[4], adjnnz[4], incnnz[3];
    for (int r = 0; r < 4; ++r) { Nr[r] = in_sizes[r] / CH; adjnnz[r] = in_sizes[4 + 3 * r]; }
    for (int r = 0; r < 3; ++r) incnnz[r] = in_sizes[16 + 3 * r];
    int Nmax = 0;
    for (int r = 0; r < 4; ++r) if (Nr[r] > Nmax) Nmax = Nr[r];
    size_t totalN = (size_t)Nr[0] + Nr[1] + Nr[2] + Nr[3];
    size_t totAdj = 0; for (int r = 0; r < 4; ++r) totAdj += adjnnz[r];
    size_t totInc = 0; for (int r = 0; r < 3; ++r) totInc += incnnz[r];
    size_t totEdges = totAdj + 2 * totInc;

    // segment bases in the concatenated row-count / rowptr arrays
    // order: adj0..adj3, incR0..incR2 (rows rank s), incC0..incC2 (rows rank s+1)
    int baseAdj[4], baseIncR[3], baseIncC[3];
    int acc_rows = 0;
    for (int r = 0; r < 4; ++r) { baseAdj[r] = acc_rows; acc_rows += Nr[r]; }
    for (int s = 0; s < 3; ++s) { baseIncR[s] = acc_rows; acc_rows += Nr[s]; }
    for (int s = 0; s < 3; ++s) { baseIncC[s] = acc_rows; acc_rows += Nr[s + 1]; }
    int totalRows = acc_rows;
    int nb = (totalRows + 4095) / 4096;

    // ---- workspace layout (~225 MB) ----
    char* ws = (char*)d_ws;
    size_t off = 0;
    auto take = [&](size_t bytes) { char* p = ws + off; off += (bytes + 255) & ~(size_t)255; return p; };
    unsigned short* xbuf  = (unsigned short*)take(totalN * CH * 2);
    unsigned short* xsave = (unsigned short*)take((size_t)Nmax * CH * 2);
    unsigned short* yS    = (unsigned short*)take((size_t)Nmax * CH * 2);
    unsigned short* yH    = (unsigned short*)take((size_t)Nmax * CH * 2);
    unsigned short* yL    = (unsigned short*)take((size_t)Nmax * CH * 2);
    unsigned short* WsT   = (unsigned short*)take((size_t)8 * 16384 * 2);
    unsigned short* WhT   = (unsigned short*)take((size_t)6 * 16384 * 2);
    unsigned short* WlT   = (unsigned short*)take((size_t)6 * 16384 * 2);
    int*  cntG   = (int*)take((size_t)totalRows * 4);
    int*  rowptrG= (int*)take(((size_t)totalRows + 1) * 4);
    int*  part   = (int*)take((size_t)nb * 4);
    int2* eArena = (int2*)take(totEdges * 8);
    (void)ws_size;

    unsigned short* x[4];
    {
        size_t o = 0;
        for (int r = 0; r < 4; ++r) { x[r] = xbuf + o; o += (size_t)Nr[r] * CH; }
    }

    // ---- CSR build ----
    k_zero_i<<<(totalRows + 255) / 256, 256, 0, stream>>>(cntG, totalRows);
    for (int r = 0; r < 4; ++r)
        k_hist<<<(adjnnz[r] + 255) / 256, 256, 0, stream>>>(arow[r], cntG + baseAdj[r], adjnnz[r]);
    for (int s = 0; s < 3; ++s)
        k_hist<<<(incnnz[s] + 255) / 256, 256, 0, stream>>>(irow[s], cntG + baseIncR[s], incnnz[s]);
    for (int s = 0; s < 3; ++s)
        k_hist<<<(incnnz[s] + 255) / 256, 256, 0, stream>>>(icol[s], cntG + baseIncC[s], incnnz[s]);
    k_scan_partial<<<nb, 256, 0, stream>>>(cntG, part, totalRows);
    k_scan_part<<<1, 256, 0, stream>>>(part, nb, rowptrG + totalRows);
    k_scan_final<<<nb, 256, 0, stream>>>(cntG, part, rowptrG, cntG, totalRows);
    for (int r = 0; r < 4; ++r)
        k_fill<<<(adjnnz[r] + 255) / 256, 256, 0, stream>>>(arow[r], acol[r], aval[r], cntG + baseAdj[r], eArena, adjnnz[r]);
    for (int s = 0; s < 3; ++s)
        k_fill<<<(incnnz[s] + 255) / 256, 256, 0, stream>>>(irow[s], icol[s], ival[s], cntG + baseIncR[s], eArena, incnnz[s]);
    for (int s = 0; s < 3; ++s)
        k_fill<<<(incnnz[s] + 255) / 256, 256, 0, stream>>>(icol[s], irow[s], ival[s], cntG + baseIncC[s], eArena, incnnz[s]);

    // ---- input conversion + weight transpose/convert ----
    for (int r = 0; r < 4; ++r) {
        int n = Nr[r] * CH;
        k_f2bf<<<(n + 255) / 256, 256, 0, stream>>>(xin[r], x[r], n);
    }
    k_wt<<<(8 * 16384 + 255) / 256, 256, 0, stream>>>(W_same, WsT, 8);
    k_wt<<<(6 * 16384 + 255) / 256, 256, 0, stream>>>(W_h2l, WhT, 6);
    k_wt<<<(6 * 16384 + 255) / 256, 256, 0, stream>>>(W_l2h, WlT, 6);

    // ---- layers ----
    for (int l = 0; l < 2; ++l) {
        for (int r = 0; r < 4; ++r) {
            int M = Nr[r];
            k_gemm<<<(M + 127) / 128, 256, 0, stream>>>(x[r], WsT + (((size_t)(l * 4 + r)) << 14), yS, M);
            if (r < 3) {
                int Ms = Nr[r + 1];
                k_gemm<<<(Ms + 127) / 128, 256, 0, stream>>>(x[r + 1], WhT + (((size_t)(l * 3 + r)) << 14), yH, Ms);
            }
            if (r > 0) {
                int Ms = Nr[r - 1];
                k_gemm<<<(Ms + 127) / 128, 256, 0, stream>>>(xsave, WlT + (((size_t)(l * 3 + r - 1)) << 14), yL, Ms);
            }
            if (r < 3) {
                int n16 = M * 16;
                k_copy16<<<(n16 + 255) / 256, 256, 0, stream>>>((const int4*)x[r], (int4*)xsave, n16);
            }
            int hasH = (r < 3) ? 1 : 0;
            int hasL = (r > 0) ? 1 : 0;
            const int* rpA = rowptrG + baseAdj[r];
            const int* rpH = hasH ? (rowptrG + baseIncR[r])     : rpA;
            const int* rpL = hasL ? (rowptrG + baseIncC[r - 1]) : rpA;
            k_gather<<<(M + 3) / 4, 256, 0, stream>>>(
                rpA, yS, rpH, yH, hasH, rpL, yL, hasL, eArena, x[r], M);
        }
    }

    k_out<<<(Nr[0] + 7) / 8, 128, 0, stream>>>(x[0], W_out, b_out, (float*)d_out, Nr[0]);
}

// Round 5
// 1214.329 us; speedup vs baseline: 9.4221x; 1.0876x over previous
//
#include <hip/hip_runtime.h>

#define CH 128

typedef __attribute__((ext_vector_type(8))) short short8;
typedef __attribute__((ext_vector_type(4))) float floatx4;

__device__ __forceinline__ float bf2f(unsigned short u) {
    union { unsigned int i; float f; } v; v.i = ((unsigned int)u) << 16; return v.f;
}
__device__ __forceinline__ unsigned short f2bf(float f) {
    union { float f; unsigned int i; } v; v.f = f;
    unsigned int r = v.i + 0x7FFF + ((v.i >> 16) & 1);  // RNE
    return (unsigned short)(r >> 16);
}

// ---------------- utility kernels ----------------

__global__ __launch_bounds__(256) void k_zero_i(int* __restrict__ p, int n) {
    int i = blockIdx.x * 256 + threadIdx.x;
    if (i < n) p[i] = 0;
}

__global__ __launch_bounds__(256) void k_copy16(const int4* __restrict__ s, int4* __restrict__ d, int n16) {
    int i = blockIdx.x * 256 + threadIdx.x;
    if (i < n16) d[i] = s[i];
}

// all 20 weight mats (8 Ws, 6 Wh, 6 Wl) f32 (k,n) -> one bf16 arena (n,k)
__global__ __launch_bounds__(256) void k_wt_all(const float* __restrict__ Ws,
                                                const float* __restrict__ Wh,
                                                const float* __restrict__ Wl,
                                                unsigned short* __restrict__ WT) {
    int i = blockIdx.x * 256 + threadIdx.x;
    if (i >= (20 << 14)) return;
    int mat = i >> 14, rem = i & 16383;
    int k = rem >> 7, n = rem & 127;
    float w;
    if (mat < 8)       w = Ws[(mat << 14) + rem];
    else if (mat < 14) w = Wh[((mat - 8) << 14) + rem];
    else               w = Wl[((mat - 14) << 14) + rem];
    WT[(mat << 14) + (n << 7) + k] = f2bf(w);
}

// ---------------- CSR build (concatenated, hierarchical scan) ----------------

struct Segs {
    const int*   row[10];
    const int*   col[10];
    const float* val[10];
    int base[10];    // row-space base in cnt/rowptr arena
    int nnz[10];
    int start[10];   // first block of this segment
};

__device__ __forceinline__ int seg_of(const Segs& sg, int blk) {
    int s = 0;
    for (int k = 1; k < 10; ++k) if (blk >= sg.start[k]) s = k;
    return s;
}

__global__ __launch_bounds__(256) void k_hist_all(Segs sg, int* __restrict__ cnt) {
    int s = seg_of(sg, blockIdx.x);
    int i = (blockIdx.x - sg.start[s]) * 256 + threadIdx.x;
    if (i < sg.nnz[s]) atomicAdd(&cnt[sg.base[s] + sg.row[s][i]], 1);
}

__global__ __launch_bounds__(256) void k_fill_all(Segs sg, int* __restrict__ cursor,
                                                  int2* __restrict__ edg) {
    int s = seg_of(sg, blockIdx.x);
    int i = (blockIdx.x - sg.start[s]) * 256 + threadIdx.x;
    if (i >= sg.nnz[s]) return;
    int p = atomicAdd(&cursor[sg.base[s] + sg.row[s][i]], 1);
    edg[p] = make_int2(sg.col[s][i], __float_as_int(sg.val[s][i]));
}

// block b sums cnt[b*4096 .. +4095] -> part[b]
__global__ __launch_bounds__(256) void k_scan_partial(const int* __restrict__ cnt, int* __restrict__ part, int n) {
    __shared__ int swt[4];
    int t = threadIdx.x, lane = t & 63, w = t >> 6;
    int base = blockIdx.x * 4096 + t * 16;
    int s = 0;
#pragma unroll
    for (int k = 0; k < 16; ++k) {
        int i = base + k;
        if (i < n) s += cnt[i];
    }
    for (int off = 1; off < 64; off <<= 1) s += __shfl_xor(s, off, 64);
    if (lane == 0) swt[w] = s;
    __syncthreads();
    if (t == 0) part[blockIdx.x] = swt[0] + swt[1] + swt[2] + swt[3];
}

__global__ __launch_bounds__(256) void k_scan_part(int* __restrict__ part, int nb, int* __restrict__ totalOut) {
    __shared__ int swt[4];
    __shared__ int scarry;
    int t = threadIdx.x, lane = t & 63, w = t >> 6;
    if (t == 0) scarry = 0;
    __syncthreads();
    for (int base = 0; base < nb; base += 256) {
        int i = base + t;
        int v = (i < nb) ? part[i] : 0;
        int incl = v;
        for (int off = 1; off < 64; off <<= 1) {
            int u = __shfl_up(incl, off, 64);
            if (lane >= off) incl += u;
        }
        if (lane == 63) swt[w] = incl;
        __syncthreads();
        int waveoff = 0;
        for (int k = 0; k < w; ++k) waveoff += swt[k];
        int running = scarry;
        if (i < nb) part[i] = running + waveoff + incl - v;
        __syncthreads();
        if (t == 255) scarry = running + waveoff + incl;
        __syncthreads();
    }
    if (t == 0) *totalOut = scarry;
}

__global__ __launch_bounds__(256) void k_scan_final(const int* __restrict__ cnt, const int* __restrict__ part,
                                                    int* __restrict__ rowptr, int* __restrict__ cursor, int n) {
    __shared__ int swt[4];
    int t = threadIdx.x, lane = t & 63, w = t >> 6;
    int base = blockIdx.x * 4096 + t * 16;
    int v[16];
    int s = 0;
#pragma unroll
    for (int k = 0; k < 16; ++k) {
        int i = base + k;
        v[k] = (i < n) ? cnt[i] : 0;
        s += v[k];
    }
    int incl = s;
    for (int off = 1; off < 64; off <<= 1) {
        int u = __shfl_up(incl, off, 64);
        if (lane >= off) incl += u;
    }
    if (lane == 63) swt[w] = incl;
    __syncthreads();
    int waveoff = 0;
    for (int k = 0; k < w; ++k) waveoff += swt[k];
    int run = part[blockIdx.x] + waveoff + incl - s;
#pragma unroll
    for (int k = 0; k < 16; ++k) {
        int i = base + k;
        if (i < n) { rowptr[i] = run; cursor[i] = run; }
        run += v[k];
    }
}

// ---------------- GEMM: Y(MxC) = A(MxC) @ B(CxC) ----------------

__device__ __forceinline__ int lds_idx(int r, int koff) {
    return (r << 7) + ((((koff >> 3) ^ (r & 15))) << 3);
}

__device__ __forceinline__ void gemm_core(const unsigned short* sA, const unsigned short* sB,
                                          unsigned short* __restrict__ Y, int M, int row0, int t) {
    const int wave = t >> 6;
    const int lane = t & 63;
    const int quad = lane >> 4;
    const int l16  = lane & 15;
    const int rbase = wave * 32;

    floatx4 acc[2][8];
    for (int i = 0; i < 2; ++i)
        for (int j = 0; j < 8; ++j) acc[i][j] = (floatx4){0.f, 0.f, 0.f, 0.f};

    for (int kk = 0; kk < 4; ++kk) {
        int ko = kk * 32 + quad * 8;
        short8 a0 = *(const short8*)(&sA[lds_idx(rbase + l16, ko)]);
        short8 a1 = *(const short8*)(&sA[lds_idx(rbase + 16 + l16, ko)]);
        for (int j = 0; j < 8; ++j) {
            short8 b = *(const short8*)(&sB[lds_idx(j * 16 + l16, ko)]);
            acc[0][j] = __builtin_amdgcn_mfma_f32_16x16x32_bf16(a0, b, acc[0][j], 0, 0, 0);
            acc[1][j] = __builtin_amdgcn_mfma_f32_16x16x32_bf16(a1, b, acc[1][j], 0, 0, 0);
        }
    }

    for (int i = 0; i < 2; ++i) {
        int rg0 = row0 + rbase + i * 16 + quad * 4;
        for (int reg = 0; reg < 4; ++reg) {
            int rg = rg0 + reg;
            if (rg >= M) continue;
            unsigned short* yr = Y + (size_t)rg * CH;
            for (int j = 0; j < 8; ++j)
                yr[j * 16 + l16] = f2bf(acc[i][j][reg]);
        }
    }
}

__global__ __launch_bounds__(256) void k_gemm(const unsigned short* __restrict__ A,
                                              const unsigned short* __restrict__ Bt,
                                              unsigned short* __restrict__ Y, int M) {
    __shared__ __align__(16) unsigned short sA[128 * 128];
    __shared__ __align__(16) unsigned short sB[128 * 128];
    const int t = threadIdx.x;
    const int row0 = blockIdx.x * 128;

    for (int it = 0; it < 8; ++it) {
        int chunk = it * 256 + t;
        int r = chunk >> 4;
        int cidx = chunk & 15;
        int coff = cidx << 3;
        int sidx = (r << 7) + (((cidx ^ (r & 15))) << 3);
        *(float4*)(&sB[sidx]) = *(const float4*)(Bt + (r << 7) + coff);
        int gr = row0 + r;
        float4 av = make_float4(0.f, 0.f, 0.f, 0.f);
        if (gr < M) av = *(const float4*)(A + (size_t)gr * CH + coff);
        *(float4*)(&sA[sidx]) = av;
    }
    __syncthreads();
    gemm_core(sA, sB, Y, M, row0, t);
}

// A in f32 (layer-1 inputs); converts to bf16 during staging
__global__ __launch_bounds__(256) void k_gemm_f32(const float* __restrict__ A,
                                                  const unsigned short* __restrict__ Bt,
                                                  unsigned short* __restrict__ Y, int M) {
    __shared__ __align__(16) unsigned short sA[128 * 128];
    __shared__ __align__(16) unsigned short sB[128 * 128];
    const int t = threadIdx.x;
    const int row0 = blockIdx.x * 128;

    for (int it = 0; it < 8; ++it) {
        int chunk = it * 256 + t;
        int r = chunk >> 4;
        int cidx = chunk & 15;
        int coff = cidx << 3;
        int sidx = (r << 7) + (((cidx ^ (r & 15))) << 3);
        *(float4*)(&sB[sidx]) = *(const float4*)(Bt + (r << 7) + coff);
        int gr = row0 + r;
        unsigned short us[8];
        if (gr < M) {
            const float* ar = A + (size_t)gr * CH + coff;
            float4 f0 = *(const float4*)ar;
            float4 f1 = *(const float4*)(ar + 4);
            us[0] = f2bf(f0.x); us[1] = f2bf(f0.y); us[2] = f2bf(f0.z); us[3] = f2bf(f0.w);
            us[4] = f2bf(f1.x); us[5] = f2bf(f1.y); us[6] = f2bf(f1.z); us[7] = f2bf(f1.w);
        } else {
            for (int k = 0; k < 8; ++k) us[k] = 0;
        }
        *(float4*)(&sA[sidx]) = *(const float4*)us;
    }
    __syncthreads();
    gemm_core(sA, sB, Y, M, row0, t);
}

// ---------------- fused gather (adj + h2l + l2h) + sigmoid ----------------
// one wave per row. Edges are wave-uniform -> scalar loads (s_load), edge value
// used as SGPR operand, y-row base scalar -> saddr-form global_load per lane.

__device__ __forceinline__ void gseg(const int* __restrict__ rp, const int2* __restrict__ eg,
                                     const unsigned short* __restrict__ y,
                                     int wrow, int coff, float& a0, float& a1) {
    int jb = __builtin_amdgcn_readfirstlane(rp[wrow]);
    int je = __builtin_amdgcn_readfirstlane(rp[wrow + 1]);
    int j = jb;
    for (; j + 4 <= je; j += 4) {
        int2 e0 = eg[j];
        int2 e1 = eg[j + 1];
        int2 e2 = eg[j + 2];
        int2 e3 = eg[j + 3];
        unsigned int u0 = *(const unsigned int*)(y + (((size_t)(unsigned)e0.x) << 7) + coff);
        unsigned int u1 = *(const unsigned int*)(y + (((size_t)(unsigned)e1.x) << 7) + coff);
        unsigned int u2 = *(const unsigned int*)(y + (((size_t)(unsigned)e2.x) << 7) + coff);
        unsigned int u3 = *(const unsigned int*)(y + (((size_t)(unsigned)e3.x) << 7) + coff);
        float v0 = __int_as_float(e0.y), v1 = __int_as_float(e1.y);
        float v2 = __int_as_float(e2.y), v3 = __int_as_float(e3.y);
        a0 += v0 * __int_as_float(u0 << 16);
        a1 += v0 * __int_as_float(u0 & 0xffff0000u);
        a0 += v1 * __int_as_float(u1 << 16);
        a1 += v1 * __int_as_float(u1 & 0xffff0000u);
        a0 += v2 * __int_as_float(u2 << 16);
        a1 += v2 * __int_as_float(u2 & 0xffff0000u);
        a0 += v3 * __int_as_float(u3 << 16);
        a1 += v3 * __int_as_float(u3 & 0xffff0000u);
    }
    for (; j < je; ++j) {
        int2 e = eg[j];
        unsigned int u = *(const unsigned int*)(y + (((size_t)(unsigned)e.x) << 7) + coff);
        float v = __int_as_float(e.y);
        a0 += v * __int_as_float(u << 16);
        a1 += v * __int_as_float(u & 0xffff0000u);
    }
}

__global__ __launch_bounds__(256) void k_gather(
    const int* __restrict__ rpA, const unsigned short* __restrict__ yS,
    const int* __restrict__ rpH, const unsigned short* __restrict__ yH, int hasH,
    const int* __restrict__ rpL, const unsigned short* __restrict__ yL, int hasL,
    const int2* __restrict__ eArena,
    unsigned short* __restrict__ xout, int M)
{
    int wrow = blockIdx.x * 4 + (threadIdx.x >> 6);
    if (wrow >= M) return;
    wrow = __builtin_amdgcn_readfirstlane(wrow);
    int lane = threadIdx.x & 63;
    int coff = lane * 2;
    float a0 = 0.f, a1 = 0.f;

    gseg(rpA, eArena, yS, wrow, coff, a0, a1);
    if (hasH) gseg(rpH, eArena, yH, wrow, coff, a0, a1);
    if (hasL) gseg(rpL, eArena, yL, wrow, coff, a0, a1);

    float s0 = 1.0f / (1.0f + __expf(-a0));
    float s1 = 1.0f / (1.0f + __expf(-a1));
    ushort2 o;
    o.x = f2bf(s0);
    o.y = f2bf(s1);
    *(ushort2*)(xout + (size_t)wrow * CH + coff) = o;
}

// ---------------- output head ----------------

__global__ __launch_bounds__(128) void k_out(const unsigned short* __restrict__ x0,
                                             const float* __restrict__ Wout,
                                             const float* __restrict__ bout,
                                             float* __restrict__ out, int M) {
    __shared__ float sl[8][16];
    int rlocal = threadIdx.x >> 4;
    int o = threadIdx.x & 15;
    int rowi = blockIdx.x * 8 + rlocal;
    float acc = 0.f;
    if (rowi < M && o < 10) {
        const unsigned short* xr = x0 + (size_t)rowi * CH;
        for (int k = 0; k < CH; ++k)
            acc += bf2f(xr[k]) * Wout[k * 10 + o];
        acc += bout[o];
    }
    sl[rlocal][o] = acc;
    __syncthreads();
    if (rowi < M && o < 10) {
        float mx = -1e30f;
        for (int j = 0; j < 10; ++j) mx = fmaxf(mx, sl[rlocal][j]);
        float s = 0.f;
        for (int j = 0; j < 10; ++j) s += __expf(sl[rlocal][j] - mx);
        out[rowi * 10 + o] = __expf(sl[rlocal][o] - mx) / s;
    }
}

// ---------------- launch ----------------

extern "C" void kernel_launch(void* const* d_in, const int* in_sizes, int n_in,
                              void* d_out, int out_size, void* d_ws, size_t ws_size,
                              hipStream_t stream) {
    const float* xin[4];
    for (int r = 0; r < 4; ++r) xin[r] = (const float*)d_in[r];
    const int* arow[4]; const int* acol[4]; const float* aval[4];
    for (int r = 0; r < 4; ++r) {
        arow[r] = (const int*)d_in[4 + 3 * r];
        acol[r] = (const int*)d_in[5 + 3 * r];
        aval[r] = (const float*)d_in[6 + 3 * r];
    }
    const int* irow[3]; const int* icol[3]; const float* ival[3];
    for (int r = 0; r < 3; ++r) {
        irow[r] = (const int*)d_in[16 + 3 * r];
        icol[r] = (const int*)d_in[17 + 3 * r];
        ival[r] = (const float*)d_in[18 + 3 * r];
    }
    const float* W_same = (const float*)d_in[25];
    const float* W_h2l  = (const float*)d_in[26];
    const float* W_l2h  = (const float*)d_in[27];
    const float* W_out  = (const float*)d_in[28];
    const float* b_out  = (const float*)d_in[29];

    int Nr[4], adjnnz[4], incnnz[3];
    for (int r = 0; r < 4; ++r) { Nr[r] = in_sizes[r] / CH; adjnnz[r] = in_sizes[4 + 3 * r]; }
    for (int r = 0; r < 3; ++r) incnnz[r] = in_sizes[16 + 3 * r];
    int Nmax = 0;
    for (int r = 0; r < 4; ++r) if (Nr[r] > Nmax) Nmax = Nr[r];
    size_t totalN = (size_t)Nr[0] + Nr[1] + Nr[2] + Nr[3];
    size_t totAdj = 0; for (int r = 0; r < 4; ++r) totAdj += adjnnz[r];
    size_t totInc = 0; for (int r = 0; r < 3; ++r) totInc += incnnz[r];
    size_t totEdges = totAdj + 2 * totInc;

    // segment bases: adj0..3, incR0..2 (rows of rank s), incC0..2 (rows of rank s+1)
    int baseAdj[4], baseIncR[3], baseIncC[3];
    int acc_rows = 0;
    for (int r = 0; r < 4; ++r) { baseAdj[r] = acc_rows; acc_rows += Nr[r]; }
    for (int s = 0; s < 3; ++s) { baseIncR[s] = acc_rows; acc_rows += Nr[s]; }
    for (int s = 0; s < 3; ++s) { baseIncC[s] = acc_rows; acc_rows += Nr[s + 1]; }
    int totalRows = acc_rows;
    int nb = (totalRows + 4095) / 4096;

    // ---- workspace (~222 MB) ----
    char* ws = (char*)d_ws;
    size_t off = 0;
    auto take = [&](size_t bytes) { char* p = ws + off; off += (bytes + 255) & ~(size_t)255; return p; };
    unsigned short* xbuf  = (unsigned short*)take(totalN * CH * 2);
    unsigned short* xsave = (unsigned short*)take((size_t)Nmax * CH * 2);
    unsigned short* yS    = (unsigned short*)take((size_t)Nmax * CH * 2);
    unsigned short* yH    = (unsigned short*)take((size_t)Nmax * CH * 2);
    unsigned short* yL    = (unsigned short*)take((size_t)Nmax * CH * 2);
    unsigned short* WT    = (unsigned short*)take((size_t)20 * 16384 * 2);
    int*  cntG   = (int*)take((size_t)totalRows * 4);
    int*  rowptrG= (int*)take(((size_t)totalRows + 1) * 4);
    int*  part   = (int*)take((size_t)nb * 4);
    int2* eArena = (int2*)take(totEdges * 8);
    (void)ws_size;

    unsigned short* WsT = WT;                    // mats 0..7
    unsigned short* WhT = WT + ((size_t)8 << 14);   // mats 8..13
    unsigned short* WlT = WT + ((size_t)14 << 14);  // mats 14..19

    unsigned short* x[4];
    {
        size_t o = 0;
        for (int r = 0; r < 4; ++r) { x[r] = xbuf + o; o += (size_t)Nr[r] * CH; }
    }

    // ---- CSR build ----
    Segs sg;
    {
        int blk = 0;
        for (int r = 0; r < 4; ++r) {
            sg.row[r] = arow[r]; sg.col[r] = acol[r]; sg.val[r] = aval[r];
            sg.base[r] = baseAdj[r]; sg.nnz[r] = adjnnz[r]; sg.start[r] = blk;
            blk += (adjnnz[r] + 255) / 256;
        }
        for (int s = 0; s < 3; ++s) {
            sg.row[4 + s] = irow[s]; sg.col[4 + s] = icol[s]; sg.val[4 + s] = ival[s];
            sg.base[4 + s] = baseIncR[s]; sg.nnz[4 + s] = incnnz[s]; sg.start[4 + s] = blk;
            blk += (incnnz[s] + 255) / 256;
        }
        for (int s = 0; s < 3; ++s) {
            sg.row[7 + s] = icol[s]; sg.col[7 + s] = irow[s]; sg.val[7 + s] = ival[s];
            sg.base[7 + s] = baseIncC[s]; sg.nnz[7 + s] = incnnz[s]; sg.start[7 + s] = blk;
            blk += (incnnz[s] + 255) / 256;
        }
        k_zero_i<<<(totalRows + 255) / 256, 256, 0, stream>>>(cntG, totalRows);
        k_hist_all<<<blk, 256, 0, stream>>>(sg, cntG);
        k_scan_partial<<<nb, 256, 0, stream>>>(cntG, part, totalRows);
        k_scan_part<<<1, 256, 0, stream>>>(part, nb, rowptrG + totalRows);
        k_scan_final<<<nb, 256, 0, stream>>>(cntG, part, rowptrG, cntG, totalRows);
        k_fill_all<<<blk, 256, 0, stream>>>(sg, cntG, eArena);
    }

    // ---- weights ----
    k_wt_all<<<(20 * 16384 + 255) / 256, 256, 0, stream>>>(W_same, W_h2l, W_l2h, WT);

    // ---- layers ----
    for (int l = 0; l < 2; ++l) {
        for (int r = 0; r < 4; ++r) {
            int M = Nr[r];
            const unsigned short* bS = WsT + (((size_t)(l * 4 + r)) << 14);
            if (l == 0) k_gemm_f32<<<(M + 127) / 128, 256, 0, stream>>>(xin[r], bS, yS, M);
            else        k_gemm    <<<(M + 127) / 128, 256, 0, stream>>>(x[r],   bS, yS, M);
            if (r < 3) {
                int Ms = Nr[r + 1];
                const unsigned short* bH = WhT + (((size_t)(l * 3 + r)) << 14);
                if (l == 0) k_gemm_f32<<<(Ms + 127) / 128, 256, 0, stream>>>(xin[r + 1], bH, yH, Ms);
                else        k_gemm    <<<(Ms + 127) / 128, 256, 0, stream>>>(x[r + 1],   bH, yH, Ms);
            }
            if (r > 0) {
                int Ms = Nr[r - 1];
                const unsigned short* bL = WlT + (((size_t)(l * 3 + r - 1)) << 14);
                if (l == 0) k_gemm_f32<<<(Ms + 127) / 128, 256, 0, stream>>>(xin[r - 1], bL, yL, Ms);
                else        k_gemm    <<<(Ms + 127) / 128, 256, 0, stream>>>(xsave,      bL, yL, Ms);
            }
            // layer 2 needs old x_r preserved for rank r+1's l2h (layer 1 reads pristine d_in)
            if (l == 1 && r < 3) {
                int n16 = M * 16;
                k_copy16<<<(n16 + 255) / 256, 256, 0, stream>>>((const int4*)x[r], (int4*)xsave, n16);
            }
            int hasH = (r < 3) ? 1 : 0;
            int hasL = (r > 0) ? 1 : 0;
            const int* rpA = rowptrG + baseAdj[r];
            const int* rpH = hasH ? (rowptrG + baseIncR[r])     : rpA;
            const int* rpL = hasL ? (rowptrG + baseIncC[r - 1]) : rpA;
            k_gather<<<(M + 3) / 4, 256, 0, stream>>>(
                rpA, yS, rpH, yH, hasH, rpL, yL, hasL, eArena, x[r], M);
        }
    }

    k_out<<<(Nr[0] + 7) / 8, 128, 0, stream>>>(x[0], W_out, b_out, (float*)d_out, Nr[0]);
}